// Round 9
// baseline (99.994 us; speedup 1.0000x reference)
//
#include <hip/hip_runtime.h>

// B=2, Hi=Wi=64, Di=32, C=16, F=8, strides (2,2,2), k=3x3x3, Ho=Wo=128, Do=64.
constexpr int Bc  = 2;
constexpr int HiC = 64, WiC = 64, DiC = 32;
constexpr int Cc  = 16, Fc  = 8;
constexpr int HoC = 128, WoC = 128, DoC = 64;

constexpr int NSLAB = 18;                      // 2 hi rows x 9 wi cols, 1 KiB each
constexpr int ZOFFB = NSLAB * 1024;            // 18432: 16 B zero block
constexpr int KBUFB = ZOFFB + 16;              // 18448: bf16 kernel copy (6912 B)
constexpr int SL_SHORTS = (KBUFB + 27 * 256) / 2;   // 12680 shorts = 25360 B

typedef __attribute__((ext_vector_type(8))) short short8;   // 8 bf16 = A/B frag
typedef __attribute__((ext_vector_type(4))) float f32x4;    // MFMA accumulator

__device__ __forceinline__ unsigned pk2(float x, float y) {   // RNE f32x2 -> bf16x2
    unsigned ux = __float_as_uint(x), uy = __float_as_uint(y);
    ux += ((ux >> 16) & 1u) + 0x7FFFu;
    uy += ((uy >> 16) & 1u) + 0x7FFFu;
    return (ux >> 16) | (uy & 0xFFFF0000u);
}
__device__ __forceinline__ short8 pack8(float4 a, float4 b) {
    union { unsigned u[4]; short8 s; } r;
    r.u[0] = pk2(a.x, a.y); r.u[1] = pk2(a.z, a.w);
    r.u[2] = pk2(b.x, b.y); r.u[3] = pk2(b.z, b.w);
    return r.s;
}

// Round 17: COMPACT CODE. r5-r8 evidence: sconv ~45us with ALL pipes <15% busy
// (3% issue-slot util) and five data-path/occupancy/persistence edits null ->
// theory: I-cache thrash. Old kernel = 4 fully-unrolled doCols instantiations
// (~50 KB); every block runs all 4 CLS variants -> constant I$ miss streaming
// (~25 cy/inst effective). This version: ONE runtime-CLS body, rolled loops
// (#pragma unroll 1), KH/KW tables packed in two u32 immediates (SALU only),
// B-frags ds_read from an LDS-staged bf16 kernel copy. Same verified math:
// A[m=lane&15][k=quad*8+j]; B[k][n=lane&15]; C/D col=lane&15,row=quad*4+reg;
// E: di = baseE-bpg+16g+n-half (kd=2*half); O: kd=1, two positions via k-halves.
// KH[4][4]={{1,0,0,0},{1,1,0,0},{0,2,0,0},{0,0,2,2}} -> 2-bit packed 0xA0080501
// KW[4][4]={{1,0,0,0},{0,2,0,0},{1,1,0,0},{0,2,0,2}} -> 2-bit packed 0x88050801
__device__ __forceinline__ void colsBody(const short* __restrict__ sl,
                                         const int*   __restrict__ bp,
                                         float*       __restrict__ out,
                                         float*       __restrict__ ldsw,
                                         int b, int ho, int wo0, int wi0,
                                         int lane, int cls) {
    const unsigned KHP = 0xA0080501u, KWP = 0x88050801u;
    const int np = (cls == 0) ? 1 : ((cls == 3) ? 4 : 2);
    const int op = (np + 1) >> 1;
    const int shb = cls * 8;
    const int quad = lane >> 4, n = lane & 15;
    const int half = quad >> 1, chalf = quad & 1;
    const int chalfB = chalf * 16;

    #pragma unroll 1
    for (int cc = 0; cc < 4; ++cc) {
        const int wo   = wo0 + 2 * cc;
        const int colx = __builtin_amdgcn_readfirstlane((b * HoC + ho) * WoC + wo);
        const int bp_col = bp[colx];                     // uniform -> s_load
        const int q      = (bp_col + 1) & 1;
        const int baseE  = (bp_col + q + 1) >> 1;
        const int baseO  = (bp_col + 1 - q) >> 1;

        f32x4 accE0{0.f,0.f,0.f,0.f}, accE1{0.f,0.f,0.f,0.f};
        f32x4 accO0{0.f,0.f,0.f,0.f}, accO1{0.f,0.f,0.f,0.f};

        #pragma unroll 1
        for (int p = 0; p < np; ++p) {                   // E taps: kd = 2*half
            const int kh = (KHP >> (shb + 2 * p)) & 3;
            const int kw = (KWP >> (shb + 2 * p)) & 3;
            int hi = (ho + 1 - kh) >> 1; hi = hi > HiC - 1 ? HiC - 1 : hi;
            int wi = (wo + 1 - kw) >> 1; wi = wi > WiC - 1 ? WiC - 1 : wi;
            const bool pvs = (kh != 0 || ho + 1 < HoC) && (kw != 0 || wo + 1 < WoC);
            const int bpg = bp[__builtin_amdgcn_readfirstlane(
                                   (b * HoC + 2 * hi) * WoC + 2 * wi)];
            const int pxo = __builtin_amdgcn_readfirstlane(
                                (((kh == 0) ? 1 : 0) * 9 + (wi - wi0)) << 10);
            const int sE  = pvs ? baseE - (bpg >> 1) : -100000;
            const int kp  = kh * 3 + kw;
            const int bofs = (n < Fc)
                ? (KBUFB + (kp * 3 + 2 * half) * 256 + n * 32 + chalfB) : ZOFFB;
            short8 bf = *(const short8*)((const char*)sl + bofs);

            int di  = sE + n - half;
            int off = ((unsigned)di < (unsigned)DiC) ? pxo + di * 32 + chalfB : ZOFFB;
            short8 a = *(const short8*)((const char*)sl + off);
            accE0 = __builtin_amdgcn_mfma_f32_16x16x32_bf16(a, bf, accE0, 0, 0, 0);
            di += 16;
            off = ((unsigned)di < (unsigned)DiC) ? pxo + di * 32 + chalfB : ZOFFB;
            a = *(const short8*)((const char*)sl + off);
            accE1 = __builtin_amdgcn_mfma_f32_16x16x32_bf16(a, bf, accE1, 0, 0, 0);
        }

        #pragma unroll 1
        for (int pp = 0; pp < op; ++pp) {                // O taps: kd=1, 2 pos/MFMA
            const int  pA   = 2 * pp;
            const bool hasB = (2 * pp + 1) < np;
            const int  pB   = hasB ? 2 * pp + 1 : pA;
            const int khA = (KHP >> (shb + 2 * pA)) & 3, kwA = (KWP >> (shb + 2 * pA)) & 3;
            const int khB = (KHP >> (shb + 2 * pB)) & 3, kwB = (KWP >> (shb + 2 * pB)) & 3;
            int hiA = (ho + 1 - khA) >> 1; hiA = hiA > HiC - 1 ? HiC - 1 : hiA;
            int wiA = (wo + 1 - kwA) >> 1; wiA = wiA > WiC - 1 ? WiC - 1 : wiA;
            int hiB = (ho + 1 - khB) >> 1; hiB = hiB > HiC - 1 ? HiC - 1 : hiB;
            int wiB = (wo + 1 - kwB) >> 1; wiB = wiB > WiC - 1 ? WiC - 1 : wiB;
            const bool pvsA = (khA != 0 || ho + 1 < HoC) && (kwA != 0 || wo + 1 < WoC);
            const bool pvsB = (khB != 0 || ho + 1 < HoC) && (kwB != 0 || wo + 1 < WoC);
            const int bpgA = bp[__builtin_amdgcn_readfirstlane(
                                    (b * HoC + 2 * hiA) * WoC + 2 * wiA)];
            const int bpgB = bp[__builtin_amdgcn_readfirstlane(
                                    (b * HoC + 2 * hiB) * WoC + 2 * wiB)];
            const int pxoA = __builtin_amdgcn_readfirstlane(
                                 (((khA == 0) ? 1 : 0) * 9 + (wiA - wi0)) << 10);
            const int pxoB = __builtin_amdgcn_readfirstlane(
                                 (((khB == 0) ? 1 : 0) * 9 + (wiB - wi0)) << 10);
            const int sOA = pvsA ? baseO - (bpgA >> 1) : -100000;
            const int sOB = (hasB && pvsB) ? baseO - (bpgB >> 1) : -100000;
            const int sOs = half ? sOB : sOA;            // per-lane select
            const int pxs = half ? pxoB : pxoA;
            const int kps = half ? khB * 3 + kwB : khA * 3 + kwA;
            const int bofs = (n < Fc && (!half || hasB))
                ? (KBUFB + (kps * 3 + 1) * 256 + n * 32 + chalfB) : ZOFFB;
            short8 bf = *(const short8*)((const char*)sl + bofs);

            int di  = sOs + n;
            int off = ((unsigned)di < (unsigned)DiC) ? pxs + di * 32 + chalfB : ZOFFB;
            short8 a = *(const short8*)((const char*)sl + off);
            accO0 = __builtin_amdgcn_mfma_f32_16x16x32_bf16(a, bf, accO0, 0, 0, 0);
            di += 16;
            off = ((unsigned)di < (unsigned)DiC) ? pxs + di * 32 + chalfB : ZOFFB;
            a = *(const short8*)((const char*)sl + off);
            accO1 = __builtin_amdgcn_mfma_f32_16x16x32_bf16(a, bf, accO1, 0, 0, 0);
        }

        // Wave-private LDS transpose: C/D (row=quad*4+r, col=n) -> [do][f] rows,
        // then fully-coalesced 2 KiB column store (r4 lesson: keep this form).
        __builtin_amdgcn_wave_barrier();
        if (n < Fc) {
            #pragma unroll
            for (int rr = 0; rr < 4; ++rr) {
                int m2 = quad * 4 + rr;
                ldsw[(2 * m2 + q) * Fc + n]     = accE0[rr];
                ldsw[(2 * m2 + 1 - q) * Fc + n] = accO0[rr];
                m2 += 16;
                ldsw[(2 * m2 + q) * Fc + n]     = accE1[rr];
                ldsw[(2 * m2 + 1 - q) * Fc + n] = accO1[rr];
            }
        }
        __builtin_amdgcn_wave_barrier();
        float* outc = out + (size_t)colx * (DoC * Fc);
        *(float4*)(outc + lane * 8)     = *(const float4*)(ldsw + lane * 8);
        *(float4*)(outc + lane * 8 + 4) = *(const float4*)(ldsw + lane * 8 + 4);
        __builtin_amdgcn_wave_barrier();
    }
}

__global__ __launch_bounds__(256, 4)
void sconv_mfma(const float* __restrict__ img, const int* __restrict__ bp,
                const float* __restrict__ kern, float* __restrict__ out) {
    __shared__ alignas(16) short sl[SL_SHORTS];        // slabs + zero + kbuf (24.8 KiB)
    __shared__ float ldsT[4 * DoC * Fc];               // 8 KiB transpose scratch
    const int t = threadIdx.x, wv = t >> 6, lane = t & 63;
    const int b = blockIdx.z, r = blockIdx.y;          // ho pair {2r, 2r+1}
    const int wo0 = (blockIdx.x << 4) + (wv & 1) + ((wv >> 1) << 3);
    const int wi0 = blockIdx.x << 3;                   // leftmost staged wi
    float* ldsw = ldsT + wv * (DoC * Fc);

    // slab staging w/ fused f32->bf16 (rows r=kh1/2, r+1=kh0), rolled loop.
    const int hi0 = r;
    int hi1 = r + 1; if (hi1 > HiC - 1) hi1 = HiC - 1;
    #pragma unroll 1
    for (int s = wv; s < NSLAB; s += 4) {
        const int hi = (s >= 9) ? hi1 : hi0;
        int wi = wi0 + ((s >= 9) ? s - 9 : s); if (wi > WiC - 1) wi = WiC - 1;
        const float* g = img + (((b * HiC + hi) * WiC + wi) << 9) + lane * 8;
        *(short8*)&sl[(s << 9) + lane * 8] =
            pack8(*(const float4*)g, *(const float4*)(g + 4));
    }
    // kernel staging f32->bf16: 3456 elems = 1728 pairs (all blocks read same
    // 13.8 KB -> L2-hot). Linear copy preserves fragment layout.
    #pragma unroll 1
    for (int i = t; i < 1728; i += 256)
        ((unsigned*)((char*)sl + KBUFB))[i] = pk2(kern[2 * i], kern[2 * i + 1]);
    if (t < 8) sl[ZOFFB / 2 + t] = 0;                  // 16 B zero block
    __syncthreads();

    // hs loop NOT unrolled: one shared code copy for all CLS (I$-friendly).
    const int p = wv & 1;
    #pragma unroll 1
    for (int hs = 0; hs < 2; ++hs)
        colsBody(sl, bp, out, ldsw, b, 2 * r + hs, wo0, wi0, lane, 2 * hs + p);
}

extern "C" void kernel_launch(void* const* d_in, const int* in_sizes, int n_in,
                              void* d_out, int out_size, void* d_ws, size_t ws_size,
                              hipStream_t stream) {
    const float* images = (const float*)d_in[0];
    const int*   bp     = (const int*)d_in[1];
    const float* kern   = (const float*)d_in[2];
    float* out = (float*)d_out;
    (void)d_ws; (void)ws_size;   // ws untouched (poison fill unconditional anyway)

    dim3 grid(WoC / 16, HoC / 2, Bc), block(256);   // 8 x 64 x 2 = 1024 blocks
    hipLaunchKernelGGL(sconv_mfma, grid, block, 0, stream,
                       images, bp, kern, out);
}